// Round 1
// baseline (386.688 us; speedup 1.0000x reference)
//
#include <hip/hip_runtime.h>
#include <math.h>

#define B_TOTAL 1048576
#define N_IMG   4096
#define EMB     64
#define CHUNK   1024                 // rows per block in partial pass
#define NBLK    (B_TOTAL / CHUNK)    // 1024 blocks
#define RPQ     (CHUNK / 64)         // 16 contiguous rows per 4-lane quad

// ws layout (floats):
//   [0      .. 4095]  d[n]    (softmax denominators, atomically accumulated)
//   [4096   .. 8191]  num[n]  (weighted-value numerators)
//   [8192   .. 8255]  u[e] = sum_h w_value[e][h]*w_out[h]
//   [8256]            c    = b_value@w_out + b_out
//   [8257]            bout = b_out

// Quad (4-lane) butterfly sum via DPP quad_perm — pure VALU, no DS pipe.
// 0xB1 = quad_perm[1,0,3,2] (xor 1), 0x4E = quad_perm[2,3,0,1] (xor 2).
__device__ __forceinline__ float quad_sum(float x) {
    x += __int_as_float(__builtin_amdgcn_update_dpp(
            0, __float_as_int(x), 0xB1, 0xF, 0xF, true));
    x += __int_as_float(__builtin_amdgcn_update_dpp(
            0, __float_as_int(x), 0x4E, 0xF, 0xF, true));
    return x;
}

__device__ __forceinline__ float dot4(float4 a, float4 b) {
    return a.x * b.x + a.y * b.y + a.z * b.z + a.w * b.w;
}

__global__ void init_kernel(const float* __restrict__ w_value,
                            const float* __restrict__ b_value,
                            const float* __restrict__ w_out,
                            const float* __restrict__ b_out,
                            float* __restrict__ ws) {
    int t = blockIdx.x * blockDim.x + threadIdx.x;
    if (t < 2 * N_IMG) {
        ws[t] = 0.f;                      // zero d[] and num[] (ws is poisoned)
    } else if (t < 2 * N_IMG + EMB) {
        int e = t - 2 * N_IMG;
        float acc = 0.f;
        for (int h = 0; h < EMB; ++h) acc += w_value[e * EMB + h] * w_out[h];
        ws[2 * N_IMG + e] = acc;          // u[e]
        if (e == 0) {
            float c = 0.f;
            for (int h = 0; h < EMB; ++h) c += b_value[h] * w_out[h];
            ws[2 * N_IMG + EMB]     = c + b_out[0];   // c
            ws[2 * N_IMG + EMB + 1] = b_out[0];       // bout
        }
    }
}

__global__ __launch_bounds__(256) void partial_kernel(
    const float* __restrict__ emb,
    const int*   __restrict__ ids,
    const float* __restrict__ w_attn,
    const float* __restrict__ ws,
    float*       __restrict__ d_acc,     // ws[0..4095]
    float*       __restrict__ num_acc) { // ws[4096..8191]
    const int tid  = threadIdx.x;
    const int sub  = tid & 3;            // lane within quad
    const int quad = tid >> 2;           // 64 quads per block
    const int base = blockIdx.x * CHUNK + quad * RPQ;  // first row of this quad

    // Lane sub owns interleaved columns {sub*4 + 16k : k=0..3}; per load inst
    // the 4 lanes of a quad read a contiguous 64B chunk of their row.
    const float4* wa4 = reinterpret_cast<const float4*>(w_attn);
    const float4* uu4 = reinterpret_cast<const float4*>(ws + 2 * N_IMG);
    const float4 wa0 = wa4[sub], wa1 = wa4[sub + 4],
                 wa2 = wa4[sub + 8], wa3 = wa4[sub + 12];
    const float4 uu0 = uu4[sub], uu1 = uu4[sub + 4],
                 uu2 = uu4[sub + 8], uu3 = uu4[sub + 12];

    int   cur_id  = ids[base];           // quad-uniform
    float acc_d   = 0.f;                 // replicated across the 4 lanes
    float acc_num = 0.f;                 // per-lane PARTIAL of numerator

    auto flush = [&]() {
        float nsum = quad_sum(acc_num);  // reduce per-lane partials (2 DPP adds)
        if (sub == 0) {
            atomicAdd(&d_acc[cur_id],   acc_d);
            atomicAdd(&num_acc[cur_id], nsum);
        }
    };

    // 1-deep software pipeline: next row's loads issue before this row's
    // (rare) flush branch, so the atomic can't fence the prefetch.
    const float4* rp = reinterpret_cast<const float4*>(emb + (size_t)base * EMB);
    float4 n0 = rp[sub], n1 = rp[sub + 4], n2 = rp[sub + 8], n3 = rp[sub + 12];
    int nrid = cur_id;

    #pragma unroll
    for (int i = 0; i < RPQ; ++i) {
        const float4 e0 = n0, e1 = n1, e2 = n2, e3 = n3;
        const int rid = nrid;
        if (i + 1 < RPQ) {
            const float4* np = reinterpret_cast<const float4*>(
                emb + (size_t)(base + i + 1) * EMB);
            n0 = np[sub];     n1 = np[sub + 4];
            n2 = np[sub + 8]; n3 = np[sub + 12];
            nrid = ids[base + i + 1];
        }
        float s = dot4(e0, wa0) + dot4(e1, wa1) + dot4(e2, wa2) + dot4(e3, wa3);
        float v = dot4(e0, uu0) + dot4(e1, uu1) + dot4(e2, uu2) + dot4(e3, uu3);
        s = quad_sum(s);                 // full score on all 4 lanes (2 DPP adds)
        if (rid != cur_id) {             // quad-uniform branch, rare (contig rows)
            flush();
            acc_d = 0.f; acc_num = 0.f; cur_id = rid;
        }
        const float e = __expf(s);       // max-free: |s| <~ 4, exact-safe in fp32
        acc_d   += e;
        acc_num += e * v;                // v stays per-lane partial
    }
    flush();
}

__global__ void finalize_kernel(const float* __restrict__ ws,
                                float* __restrict__ out) {
    int n = blockIdx.x * blockDim.x + threadIdx.x;
    if (n >= N_IMG) return;
    const float d    = ws[n];
    const float num  = ws[N_IMG + n];
    const float c    = ws[2 * N_IMG + EMB];
    const float bout = ws[2 * N_IMG + EMB + 1];
    const float rv   = (d != 0.f) ? (num / d + c) : bout;  // empty seg -> b_out
    out[(size_t)B_TOTAL + n]         = rv;        // r_images
    out[(size_t)B_TOTAL + N_IMG + n] = (float)n;  // unique_ids
}

__global__ __launch_bounds__(256) void scatter_kernel(
    const int*   __restrict__ ids,
    const float* __restrict__ r_img,   // = out + B_TOTAL (16 KB, L2-resident)
    float*       __restrict__ out) {
    int i = blockIdx.x * blockDim.x + threadIdx.x;   // 4 rows per thread
    int4 id4 = reinterpret_cast<const int4*>(ids)[i];
    float4 o;
    o.x = r_img[id4.x]; o.y = r_img[id4.y];
    o.z = r_img[id4.z]; o.w = r_img[id4.w];
    reinterpret_cast<float4*>(out)[i] = o;
}

extern "C" void kernel_launch(void* const* d_in, const int* in_sizes, int n_in,
                              void* d_out, int out_size, void* d_ws, size_t ws_size,
                              hipStream_t stream) {
    const float* emb     = (const float*)d_in[0];
    const int*   ids     = (const int*)  d_in[1];
    const float* w_attn  = (const float*)d_in[2];
    // d_in[3] = b_attn: cancels inside the segment softmax, unused
    const float* w_value = (const float*)d_in[4];
    const float* b_value = (const float*)d_in[5];
    const float* w_out   = (const float*)d_in[6];
    const float* b_out   = (const float*)d_in[7];
    float* out = (float*)d_out;
    float* ws  = (float*)d_ws;

    init_kernel<<<(2 * N_IMG + EMB + 255) / 256, 256, 0, stream>>>(
        w_value, b_value, w_out, b_out, ws);
    partial_kernel<<<NBLK, 256, 0, stream>>>(
        emb, ids, w_attn, ws, ws, ws + N_IMG);
    finalize_kernel<<<(N_IMG + 255) / 256, 256, 0, stream>>>(ws, out);
    scatter_kernel<<<B_TOTAL / (256 * 4), 256, 0, stream>>>(
        ids, out + B_TOTAL, out);
}

// Round 6
// 370.746 us; speedup vs baseline: 1.0430x; 1.0430x over previous
//
#include <hip/hip_runtime.h>
#include <math.h>

#define B_TOTAL 1048576
#define N_IMG   4096
#define EMB     64
#define CHUNK   1024                 // rows per block in partial pass
#define NBLK    (B_TOTAL / CHUNK)    // 1024 blocks
#define RPQ     (CHUNK / 64)         // 16 contiguous rows per 4-lane quad

typedef float v4f __attribute__((ext_vector_type(4)));

// ws layout (floats):
//   [0      .. 4095]  d[n]    (softmax denominators, atomically accumulated)
//   [4096   .. 8191]  num[n]  (weighted-value numerators)
//   [8192   .. 8255]  u[e] = sum_h w_value[e][h]*w_out[h]
//   [8256]            c    = b_value@w_out + b_out
//   [8257]            bout = b_out

// Quad (4-lane) butterfly sum via DPP quad_perm — pure VALU, no DS pipe.
// 0xB1 = quad_perm[1,0,3,2] (xor 1), 0x4E = quad_perm[2,3,0,1] (xor 2).
__device__ __forceinline__ float quad_sum(float x) {
    x += __int_as_float(__builtin_amdgcn_update_dpp(
            0, __float_as_int(x), 0xB1, 0xF, 0xF, true));
    x += __int_as_float(__builtin_amdgcn_update_dpp(
            0, __float_as_int(x), 0x4E, 0xF, 0xF, true));
    return x;
}

__device__ __forceinline__ float dot4(v4f a, v4f b) {
    return a.x * b.x + a.y * b.y + a.z * b.z + a.w * b.w;
}

__global__ void init_kernel(const float* __restrict__ w_value,
                            const float* __restrict__ b_value,
                            const float* __restrict__ w_out,
                            const float* __restrict__ b_out,
                            float* __restrict__ ws) {
    int t = blockIdx.x * blockDim.x + threadIdx.x;
    if (t < 2 * N_IMG) {
        ws[t] = 0.f;                      // zero d[] and num[] (ws is poisoned)
    } else if (t < 2 * N_IMG + EMB) {
        int e = t - 2 * N_IMG;
        float acc = 0.f;
        for (int h = 0; h < EMB; ++h) acc += w_value[e * EMB + h] * w_out[h];
        ws[2 * N_IMG + e] = acc;          // u[e]
        if (e == 0) {
            float c = 0.f;
            for (int h = 0; h < EMB; ++h) c += b_value[h] * w_out[h];
            ws[2 * N_IMG + EMB]     = c + b_out[0];   // c
            ws[2 * N_IMG + EMB + 1] = b_out[0];       // bout
        }
    }
}

__global__ __launch_bounds__(256) void partial_kernel(
    const float* __restrict__ emb,
    const int*   __restrict__ ids,
    const float* __restrict__ w_attn,
    const float* __restrict__ ws,
    float*       __restrict__ d_acc,     // ws[0..4095]
    float*       __restrict__ num_acc) { // ws[4096..8191]
    const int tid  = threadIdx.x;
    const int sub  = tid & 3;            // lane within quad
    const int quad = tid >> 2;           // 64 quads per block
    const int base = blockIdx.x * CHUNK + quad * RPQ;  // first row of this quad

    // Lane sub owns interleaved columns {sub*4 + 16k : k=0..3}; per load inst
    // the 4 lanes of a quad read a contiguous 64B chunk of their row.
    const v4f* wa4 = reinterpret_cast<const v4f*>(w_attn);
    const v4f* uu4 = reinterpret_cast<const v4f*>(ws + 2 * N_IMG);
    const v4f wa0 = wa4[sub], wa1 = wa4[sub + 4],
              wa2 = wa4[sub + 8], wa3 = wa4[sub + 12];
    const v4f uu0 = uu4[sub], uu1 = uu4[sub + 4],
              uu2 = uu4[sub + 8], uu3 = uu4[sub + 12];

    int   cur_id  = ids[base];           // quad-uniform
    float acc_d   = 0.f;                 // replicated across the 4 lanes
    float acc_num = 0.f;                 // per-lane PARTIAL of numerator

    auto flush = [&]() {
        float nsum = quad_sum(acc_num);  // reduce per-lane partials (2 DPP adds)
        if (sub == 0) {
            atomicAdd(&d_acc[cur_id],   acc_d);
            atomicAdd(&num_acc[cur_id], nsum);
        }
    };

    // 1-deep software pipeline; emb is read-once -> nontemporal (don't pollute
    // L2/L3, which we want holding the d/num accumulators + ids).
    const v4f* rp = reinterpret_cast<const v4f*>(emb + (size_t)base * EMB);
    v4f n0 = __builtin_nontemporal_load(rp + sub);
    v4f n1 = __builtin_nontemporal_load(rp + sub + 4);
    v4f n2 = __builtin_nontemporal_load(rp + sub + 8);
    v4f n3 = __builtin_nontemporal_load(rp + sub + 12);
    int nrid = cur_id;

    #pragma unroll
    for (int i = 0; i < RPQ; ++i) {
        const v4f e0 = n0, e1 = n1, e2 = n2, e3 = n3;
        const int rid = nrid;
        if (i + 1 < RPQ) {
            const v4f* np = reinterpret_cast<const v4f*>(
                emb + (size_t)(base + i + 1) * EMB);
            n0 = __builtin_nontemporal_load(np + sub);
            n1 = __builtin_nontemporal_load(np + sub + 4);
            n2 = __builtin_nontemporal_load(np + sub + 8);
            n3 = __builtin_nontemporal_load(np + sub + 12);
            nrid = ids[base + i + 1];
        }
        float s = dot4(e0, wa0) + dot4(e1, wa1) + dot4(e2, wa2) + dot4(e3, wa3);
        float v = dot4(e0, uu0) + dot4(e1, uu1) + dot4(e2, uu2) + dot4(e3, uu3);
        s = quad_sum(s);                 // full score on all 4 lanes (2 DPP adds)
        if (rid != cur_id) {             // quad-uniform branch, rare (contig rows)
            flush();
            acc_d = 0.f; acc_num = 0.f; cur_id = rid;
        }
        const float e = __expf(s);       // max-free: |s| <~ 4, exact-safe in fp32
        acc_d   += e;
        acc_num += e * v;                // v stays per-lane partial
    }
    flush();
}

// finalize + scatter merged: both depend only on the d/num accumulators (one
// kernel boundary after partial_kernel), not on each other. Scatter computes
// num/d + c inline -> no r_img intermediate, no extra launch.
__global__ __launch_bounds__(256) void finalize_scatter_kernel(
    const int*   __restrict__ ids,
    const float* __restrict__ ws,        // d[] / num[] / c / bout
    float*       __restrict__ out) {
    const int gid = blockIdx.x * blockDim.x + threadIdx.x;   // 4 rows per thread
    const float c    = ws[2 * N_IMG + EMB];

    // r_images + unique_ids (first 16 blocks' threads)
    if (gid < N_IMG) {
        const float d    = ws[gid];
        const float num  = ws[N_IMG + gid];
        const float bout = ws[2 * N_IMG + EMB + 1];
        out[(size_t)B_TOTAL + gid]         = (d != 0.f) ? (num / d + c) : bout;
        out[(size_t)B_TOTAL + N_IMG + gid] = (float)gid;
    }

    // r_reflections: ids present => d > 0; d/num are 32 KB, L2-resident, and
    // sorted ids make these mostly broadcast loads.
    const int4 id4 = reinterpret_cast<const int4*>(ids)[gid];
    float4 o;
    o.x = ws[N_IMG + id4.x] / ws[id4.x] + c;
    o.y = ws[N_IMG + id4.y] / ws[id4.y] + c;
    o.z = ws[N_IMG + id4.z] / ws[id4.z] + c;
    o.w = ws[N_IMG + id4.w] / ws[id4.w] + c;
    reinterpret_cast<float4*>(out)[gid] = o;
}

extern "C" void kernel_launch(void* const* d_in, const int* in_sizes, int n_in,
                              void* d_out, int out_size, void* d_ws, size_t ws_size,
                              hipStream_t stream) {
    const float* emb     = (const float*)d_in[0];
    const int*   ids     = (const int*)  d_in[1];
    const float* w_attn  = (const float*)d_in[2];
    // d_in[3] = b_attn: cancels inside the segment softmax, unused
    const float* w_value = (const float*)d_in[4];
    const float* b_value = (const float*)d_in[5];
    const float* w_out   = (const float*)d_in[6];
    const float* b_out   = (const float*)d_in[7];
    float* out = (float*)d_out;
    float* ws  = (float*)d_ws;

    init_kernel<<<(2 * N_IMG + EMB + 255) / 256, 256, 0, stream>>>(
        w_value, b_value, w_out, b_out, ws);
    partial_kernel<<<NBLK, 256, 0, stream>>>(
        emb, ids, w_attn, ws, ws, ws + N_IMG);
    finalize_scatter_kernel<<<B_TOTAL / (256 * 4), 256, 0, stream>>>(
        ids, ws, out);
}